// Round 2
// baseline (2167.622 us; speedup 1.0000x reference)
//
#include <hip/hip_runtime.h>
#include <math.h>

#define TW 64
#define TH 32
#define IMG 1024

// LDS row strides (floats). Row-stride mod 32 must be an odd multiple of 4 so
// consecutive rows shift bank-quads: 84%32=20 ok, 68%32=4 ok.
#define GSTR 84   // gray: 48 rows  (gy = y0-8 .. y0+39, gx = x0-8 .. x0+75)
#define ASTR 84   // A (vblur): 35 rows (34 used + 1 guard), ar -> gy = y0-1+ar
#define SSTR 68   // S (smooth): 34 rows, cs -> gx = x0-1+cs

// Per-scale processing. R = gaussian radius (ksize = 2R+1), off = offset into wtab.
template<int R>
__device__ __forceinline__ void do_scale(const float* __restrict__ wtab, int off,
    const float* __restrict__ gray, float* __restrict__ A, float* __restrict__ S,
    int tid, int x0, int y0, float* __restrict__ acc)
{
  // hoist this scale's weights into VGPRs (broadcast ds_read, free)
  float wl[2*R + 1];
#pragma unroll
  for (int d = 0; d <= 2*R; ++d) wl[d] = wtab[off + d];

  // ---- P1: vertical blur gray -> A. 20 quads x 9 row-segments (8x G=4 + 1x G=2).
  // Lane bank check: 8 consecutive lanes have q stepping 1 (16B) with seg wrap
  // adding 84*4 floats (bank +16) -> 8 distinct bank-quads. Conflict-free.
  if (tid < 180) {
    const int q   = tid % 20;
    const int seg = tid / 20;
    const int ys  = seg * 4;                 // first A-row of this segment
    const bool full = (seg < 8);             // seg 8 computes only rows 32,33
    float4 a4[4];
#pragma unroll
    for (int gi = 0; gi < 4; ++gi) a4[gi] = make_float4(0.f, 0.f, 0.f, 0.f);
#pragma unroll
    for (int kk = 0; kk < 4 + 2*R; ++kk) {
      const bool kok = (kk < 2 + 2*R);
      if (full || kok) {
        const float4 v = *(const float4*)&gray[(ys + 7 - R + kk)*GSTR + 4*q];
#pragma unroll
        for (int gi = 0; gi < 4; ++gi) {
          const int d = kk - gi;             // tap index 0..2R (compile-time)
          if (d >= 0 && d <= 2*R) {
            if (gi < 2 || full) {
              const float wt = wl[d];
              a4[gi].x += wt * v.x;
              a4[gi].y += wt * v.y;
              a4[gi].z += wt * v.z;
              a4[gi].w += wt * v.w;
            }
          }
        }
      }
    }
#pragma unroll
    for (int gi = 0; gi < 4; ++gi)
      if (gi < 2 || full)
        *(float4*)&A[(ys + gi)*ASTR + 4*q] = a4[gi];
  }
  __syncthreads();
  __builtin_amdgcn_sched_barrier(0);

  // ---- P2: horizontal blur A -> S (34 rows x 66 cols), force 0 outside image.
  // Mapping ar = u%34 (consecutive lanes step ROWS: bank step 20 -> 8 distinct
  // bank-quads per 8-lane group). unroll 1 keeps av[] single-instanced.
  {
    constexpr int Q0   = (7 - R) >> 2;                 // first quad rel. to col 8*cg
    constexpr int NQ   = ((14 + R) >> 2) - Q0 + 1;     // quads to load (3..6)
    constexpr int BASE = 7 - R - 4*Q0;                 // av index base
#pragma unroll 1
    for (int u = tid; u < 306; u += 256) {             // 34 rows * 9 col-groups
      const int ar = u % 34, cg = u / 34;
      float av[4*NQ];
#pragma unroll
      for (int i = 0; i < NQ; ++i)
        *(float4*)&av[4*i] = *(const float4*)&A[ar*ASTR + 8*cg + 4*(Q0 + i)];
      const int gy  = y0 - 1 + ar;
      const int gx0 = x0 - 1 + 8*cg;
      const bool rowok = ((unsigned)gy < (unsigned)IMG);
      float o8[8];
#pragma unroll
      for (int o = 0; o < 8; ++o) {
        float s = 0.f;
#pragma unroll
        for (int t = 0; t <= 2*R; ++t)
          s += wl[t] * av[o + BASE + t];
        const int gx = gx0 + o;
        // Laplacian input is smooth zero-padded by 1: outside-image slots are 0.
        o8[o] = (rowok && ((unsigned)gx < (unsigned)IMG)) ? s : 0.f;
      }
      if (cg < 8) {
        *(float4*)&S[ar*SSTR + 8*cg]     = make_float4(o8[0], o8[1], o8[2], o8[3]);
        *(float4*)&S[ar*SSTR + 8*cg + 4] = make_float4(o8[4], o8[5], o8[6], o8[7]);
      } else {                                          // last group: cols 64,65
        S[ar*SSTR + 64] = o8[0];
        S[ar*SSTR + 65] = o8[1];
      }
    }
  }
  __syncthreads();
  __builtin_amdgcn_sched_barrier(0);

  // ---- P3: 5-point Laplacian of S, accumulate |log|.
  // Mapping row = tid&31 (consecutive lanes step rows: bank step 4 -> distinct).
  {
    const int row = tid & 31, cg = tid >> 5;
    float T[12], M[12], B[12];
#pragma unroll
    for (int i = 0; i < 3; ++i) {
      *(float4*)&T[4*i] = *(const float4*)&S[(row    )*SSTR + 8*cg + 4*i];
      *(float4*)&M[4*i] = *(const float4*)&S[(row + 1)*SSTR + 8*cg + 4*i];
      *(float4*)&B[4*i] = *(const float4*)&S[(row + 2)*SSTR + 8*cg + 4*i];
    }
#pragma unroll
    for (int o = 0; o < 8; ++o) {
      const int j = o + 1;
      const float lg = T[j] + B[j] + M[j-1] + M[j+1] - 4.f*M[j];
      acc[o] += fabsf(lg);
    }
  }
  // NO barrier here: next P1 writes A (disjoint from S); the post-P1 barrier
  // orders this P3's S-reads against the next P2's S-writes.
  __builtin_amdgcn_sched_barrier(0);
}

__global__ __launch_bounds__(256, 4)
void MultiscaleLoG_kernel(const float* __restrict__ in, float* __restrict__ out)
{
  __shared__ __align__(16) float gray[48*GSTR];
  __shared__ __align__(16) float A[35*ASTR];
  __shared__ __align__(16) float S[34*SSTR];
  __shared__ float wtab[189];

  const int tid = threadIdx.x;
  const int x0 = blockIdx.x * TW;
  const int y0 = blockIdx.y * TH;
  const int b  = blockIdx.z;
  const float* __restrict__ base = in + (size_t)b * 3u * 1048576u;

  // ---- weights: 21 threads each build one normalized 1D gaussian into LDS
  if (tid < 21) {
    const int ki = tid / 3, si = tid % 3;        // ks = 3+2ki, sigma = 1+si
    const int ks = 3 + 2*ki, r = ks >> 1;
    const int woff = 3*ki*(ki + 2) + si*ks;      // cumulative offset
    const float inv2s2 = 1.f / (2.f * (float)((si + 1)*(si + 1)));
    float sum = 0.f;
    for (int i = 0; i < ks; ++i) {
      const float x = (float)(i - r);
      const float e = expf(-x*x*inv2s2);
      wtab[woff + i] = e;
      sum += e;
    }
    for (int i = 0; i < ks; ++i) wtab[woff + i] /= sum;
  }

  // ---- gray = channel mean, staged with halo; zero outside image
  const bool interior = (x0 >= 8) & (x0 + 76 <= IMG) & (y0 >= 8) & (y0 + 40 <= IMG);
#pragma unroll 1
  for (int u = tid; u < 960; u += 256) {          // 20 quads x 48 rows
    const int q = u % 20, gr = u / 20;
    const int gx = x0 - 8 + 4*q, gy = y0 - 8 + gr;
    float4 v;
    if (interior) {
      const float* p = base + (size_t)gy * IMG + gx;
      const float4 c0 = *(const float4*)p;
      const float4 c1 = *(const float4*)(p + 1048576);
      const float4 c2 = *(const float4*)(p + 2097152);
      v.x = (c0.x + c1.x + c2.x) * (1.f/3.f);
      v.y = (c0.y + c1.y + c2.y) * (1.f/3.f);
      v.z = (c0.z + c1.z + c2.z) * (1.f/3.f);
      v.w = (c0.w + c1.w + c2.w) * (1.f/3.f);
    } else {
      float t4[4];
#pragma unroll
      for (int j = 0; j < 4; ++j) {
        const int xx = gx + j;
        float s = 0.f;
        if ((unsigned)xx < (unsigned)IMG && (unsigned)gy < (unsigned)IMG) {
          const float* p = base + (size_t)gy * IMG + xx;
          s = (p[0] + p[1048576] + p[2097152]) * (1.f/3.f);
        }
        t4[j] = s;
      }
      v = make_float4(t4[0], t4[1], t4[2], t4[3]);
    }
    *(float4*)&gray[gr*GSTR + 4*q] = v;
  }
  __syncthreads();
  __builtin_amdgcn_sched_barrier(0);

  float acc[8];
#pragma unroll
  for (int i = 0; i < 8; ++i) acc[i] = 0.f;

#define DO_KS(R, KOFF) \
  do_scale<R>(wtab, (KOFF),               gray, A, S, tid, x0, y0, acc); \
  do_scale<R>(wtab, (KOFF) + (2*(R)+1),   gray, A, S, tid, x0, y0, acc); \
  do_scale<R>(wtab, (KOFF) + 2*(2*(R)+1), gray, A, S, tid, x0, y0, acc);

  DO_KS(1, 0)
  DO_KS(2, 9)
  DO_KS(3, 24)
  DO_KS(4, 45)
  DO_KS(5, 72)
  DO_KS(6, 105)
  DO_KS(7, 144)
#undef DO_KS

  // ---- coalesced output via LDS transpose (acc ownership is row=tid&31)
  __syncthreads();                         // all P3 S-reads done
  {
    const int row = tid & 31, cg = tid >> 5;
    *(float4*)&S[row*SSTR + 8*cg]     = make_float4(acc[0], acc[1], acc[2], acc[3]);
    *(float4*)&S[row*SSTR + 8*cg + 4] = make_float4(acc[4], acc[5], acc[6], acc[7]);
  }
  __syncthreads();
  {
    const int cg = tid & 7, row = tid >> 3;
    const float4 lo = *(const float4*)&S[row*SSTR + 8*cg];
    const float4 hi = *(const float4*)&S[row*SSTR + 8*cg + 4];
    float* op = out + ((size_t)b * IMG + (y0 + row)) * IMG + x0 + 8*cg;
    *(float4*)&op[0] = lo;
    *(float4*)&op[4] = hi;
  }
}

extern "C" void kernel_launch(void* const* d_in, const int* in_sizes, int n_in,
                              void* d_out, int out_size, void* d_ws, size_t ws_size,
                              hipStream_t stream) {
  (void)in_sizes; (void)n_in; (void)d_ws; (void)ws_size; (void)out_size;
  const float* in = (const float*)d_in[0];
  float* out = (float*)d_out;
  dim3 grid(IMG / TW, IMG / TH, 16);
  MultiscaleLoG_kernel<<<grid, dim3(256), 0, stream>>>(in, out);
}

// Round 3
// 1573.652 us; speedup vs baseline: 1.3774x; 1.3774x over previous
//
#include <hip/hip_runtime.h>
#include <math.h>

#define TW 64
#define TH 32
#define IMG 1024

// LDS row strides (floats). Row-stride mod 32 an odd multiple of 4 so
// consecutive rows shift bank-quads: 84%32=20, 68%32=4.
#define GSTR 84   // gray: 48 rows  (gy = y0-8 .. y0+39, gx = x0-8 .. x0+75)
#define ASTR 84   // A (vblur): 35 rows (34 used + 1 guard), ar -> gy = y0-1+ar
#define SSTR 68   // S (smooth): 34 rows, cs -> gx = x0-1+cs

// ---- compile-time Gaussian weight table (doubles, then normalized to float).
// Indexed ONLY with compile-time constants -> every weight folds to an inline
// 32-bit literal in v_fmac_f32; no LDS table, no registers, no expf preamble.
constexpr double cexp_pos(double t) {   // e^t for t >= 0 via Taylor (double)
  double term = 1.0, sum = 1.0;
  for (int i = 1; i < 120; ++i) {
    term *= t / i;
    sum += term;
    if (term < 1e-300) break;
  }
  return sum;
}
constexpr double cexp(double t) { return t < 0 ? 1.0 / cexp_pos(-t) : cexp_pos(t); }

struct WTab {
  float w[189];
  constexpr WTab() : w{} {
    int off = 0;
    for (int ki = 0; ki < 7; ++ki) {          // ks = 3 + 2*ki, r = ks/2
      const int ks = 3 + 2 * ki, r = ks >> 1;
      for (int si = 0; si < 3; ++si) {        // sigma = 1 + si
        const double s = (double)(1 + si);
        double tmp[15] = {};
        double sum = 0.0;
        for (int i = 0; i < ks; ++i) {
          const double x = (double)(i - r);
          tmp[i] = cexp(-x * x / (2.0 * s * s));
          sum += tmp[i];
        }
        for (int i = 0; i < ks; ++i) w[off + i] = (float)(tmp[i] / sum);
        off += ks;
      }
    }
  }
};
constexpr WTab WT{};

// Per-scale processing. R = radius (ksize = 2R+1), OFF = offset into WT.w.
template<int R, int OFF>
__device__ __forceinline__ void do_scale(
    const float* __restrict__ gray, float* __restrict__ A, float* __restrict__ S,
    int tid, int x0, int y0, float* __restrict__ acc)
{
  // ---- P1: vertical blur gray -> A. 20 quads x 9 row-segments (8x G=4 + 1x G=2).
  if (tid < 180) {
    const int q   = tid % 20;
    const int seg = tid / 20;
    const int ys  = seg * 4;                 // first A-row of this segment
    const bool full = (seg < 8);             // seg 8 computes only rows 32,33
    float4 a4[4];
#pragma unroll
    for (int gi = 0; gi < 4; ++gi) a4[gi] = make_float4(0.f, 0.f, 0.f, 0.f);
#pragma unroll
    for (int kk = 0; kk < 4 + 2*R; ++kk) {
      const bool kok = (kk < 2 + 2*R);
      if (full || kok) {
        const float4 v = *(const float4*)&gray[(ys + 7 - R + kk)*GSTR + 4*q];
#pragma unroll
        for (int gi = 0; gi < 4; ++gi) {
          const int d = kk - gi;             // tap index 0..2R (compile-time)
          if (d >= 0 && d <= 2*R) {
            if (gi < 2 || full) {
              const float wt = WT.w[OFF + d];   // inline literal
              a4[gi].x += wt * v.x;
              a4[gi].y += wt * v.y;
              a4[gi].z += wt * v.z;
              a4[gi].w += wt * v.w;
            }
          }
        }
      }
    }
#pragma unroll
    for (int gi = 0; gi < 4; ++gi)
      if (gi < 2 || full)
        *(float4*)&A[(ys + gi)*ASTR + 4*q] = a4[gi];
  }
  __syncthreads();

  // ---- P2: horizontal blur A -> S (34 rows x 66 cols), force 0 outside image.
  // ar = u%34: consecutive lanes step ROWS (bank step 20) -> conflict-free.
  {
    constexpr int Q0   = (7 - R) >> 2;                 // first quad rel. to col 8*cg
    constexpr int NQ   = ((14 + R) >> 2) - Q0 + 1;     // quads to load (3..6)
    constexpr int BASE = 7 - R - 4*Q0;                 // av index base
#pragma unroll 1
    for (int u = tid; u < 306; u += 256) {             // 34 rows * 9 col-groups
      const int ar = u % 34, cg = u / 34;
      float av[4*NQ];
#pragma unroll
      for (int i = 0; i < NQ; ++i)
        *(float4*)&av[4*i] = *(const float4*)&A[ar*ASTR + 8*cg + 4*(Q0 + i)];
      const int gy  = y0 - 1 + ar;
      const int gx0 = x0 - 1 + 8*cg;
      const bool rowok = ((unsigned)gy < (unsigned)IMG);
      float o8[8];
#pragma unroll
      for (int o = 0; o < 8; ++o) {
        float s = 0.f;
#pragma unroll
        for (int t = 0; t <= 2*R; ++t)
          s += WT.w[OFF + t] * av[o + BASE + t];       // inline literals
        const int gx = gx0 + o;
        // Laplacian input is smooth zero-padded by 1: outside-image slots are 0.
        o8[o] = (rowok && ((unsigned)gx < (unsigned)IMG)) ? s : 0.f;
      }
      if (cg < 8) {
        *(float4*)&S[ar*SSTR + 8*cg]     = make_float4(o8[0], o8[1], o8[2], o8[3]);
        *(float4*)&S[ar*SSTR + 8*cg + 4] = make_float4(o8[4], o8[5], o8[6], o8[7]);
      } else {                                          // last group: cols 64,65
        S[ar*SSTR + 64] = o8[0];
        S[ar*SSTR + 65] = o8[1];
      }
    }
  }
  __syncthreads();

  // ---- P3: 5-point Laplacian of S, accumulate |log|.
  // row = tid&31: consecutive lanes step rows (bank step 4) -> conflict-free.
  {
    const int row = tid & 31, cg = tid >> 5;
    float T[12], M[12], B[12];
#pragma unroll
    for (int i = 0; i < 3; ++i) {
      *(float4*)&T[4*i] = *(const float4*)&S[(row    )*SSTR + 8*cg + 4*i];
      *(float4*)&M[4*i] = *(const float4*)&S[(row + 1)*SSTR + 8*cg + 4*i];
      *(float4*)&B[4*i] = *(const float4*)&S[(row + 2)*SSTR + 8*cg + 4*i];
    }
#pragma unroll
    for (int o = 0; o < 8; ++o) {
      const int j = o + 1;
      const float lg = T[j] + B[j] + M[j-1] + M[j+1] - 4.f*M[j];
      acc[o] += fabsf(lg);
    }
  }
  // NO barrier here: next P1 writes A (disjoint from S); the post-P1 barrier
  // orders this P3's S-reads against the next P2's S-writes.
}

__global__ __launch_bounds__(256)
void MultiscaleLoG_kernel(const float* __restrict__ in, float* __restrict__ out)
{
  __shared__ __align__(16) float gray[48*GSTR];
  __shared__ __align__(16) float A[35*ASTR];
  __shared__ __align__(16) float S[34*SSTR];

  const int tid = threadIdx.x;
  const int x0 = blockIdx.x * TW;
  const int y0 = blockIdx.y * TH;
  const int b  = blockIdx.z;
  const float* __restrict__ base = in + (size_t)b * 3u * 1048576u;

  // ---- gray = channel mean, staged with halo; zero outside image
  const bool interior = (x0 >= 8) & (x0 + 76 <= IMG) & (y0 >= 8) & (y0 + 40 <= IMG);
#pragma unroll 1
  for (int u = tid; u < 960; u += 256) {          // 20 quads x 48 rows
    const int q = u % 20, gr = u / 20;
    const int gx = x0 - 8 + 4*q, gy = y0 - 8 + gr;
    float4 v;
    if (interior) {
      const float* p = base + (size_t)gy * IMG + gx;
      const float4 c0 = *(const float4*)p;
      const float4 c1 = *(const float4*)(p + 1048576);
      const float4 c2 = *(const float4*)(p + 2097152);
      v.x = (c0.x + c1.x + c2.x) * (1.f/3.f);
      v.y = (c0.y + c1.y + c2.y) * (1.f/3.f);
      v.z = (c0.z + c1.z + c2.z) * (1.f/3.f);
      v.w = (c0.w + c1.w + c2.w) * (1.f/3.f);
    } else {
      float t4[4];
#pragma unroll
      for (int j = 0; j < 4; ++j) {
        const int xx = gx + j;
        float s = 0.f;
        if ((unsigned)xx < (unsigned)IMG && (unsigned)gy < (unsigned)IMG) {
          const float* p = base + (size_t)gy * IMG + xx;
          s = (p[0] + p[1048576] + p[2097152]) * (1.f/3.f);
        }
        t4[j] = s;
      }
      v = make_float4(t4[0], t4[1], t4[2], t4[3]);
    }
    *(float4*)&gray[gr*GSTR + 4*q] = v;
  }
  __syncthreads();

  float acc[8];
#pragma unroll
  for (int i = 0; i < 8; ++i) acc[i] = 0.f;

#define DO_KS(R, KOFF) \
  do_scale<R, (KOFF)>(gray, A, S, tid, x0, y0, acc); \
  do_scale<R, (KOFF) + (2*(R)+1)>(gray, A, S, tid, x0, y0, acc); \
  do_scale<R, (KOFF) + 2*(2*(R)+1)>(gray, A, S, tid, x0, y0, acc);

  DO_KS(1, 0)
  DO_KS(2, 9)
  DO_KS(3, 24)
  DO_KS(4, 45)
  DO_KS(5, 72)
  DO_KS(6, 105)
  DO_KS(7, 144)
#undef DO_KS

  // ---- coalesced output via LDS transpose (acc ownership is row=tid&31)
  __syncthreads();                         // all P3 S-reads done
  {
    const int row = tid & 31, cg = tid >> 5;
    *(float4*)&S[row*SSTR + 8*cg]     = make_float4(acc[0], acc[1], acc[2], acc[3]);
    *(float4*)&S[row*SSTR + 8*cg + 4] = make_float4(acc[4], acc[5], acc[6], acc[7]);
  }
  __syncthreads();
  {
    const int cg = tid & 7, row = tid >> 3;
    const float4 lo = *(const float4*)&S[row*SSTR + 8*cg];
    const float4 hi = *(const float4*)&S[row*SSTR + 8*cg + 4];
    float* op = out + ((size_t)b * IMG + (y0 + row)) * IMG + x0 + 8*cg;
    *(float4*)&op[0] = lo;
    *(float4*)&op[4] = hi;
  }
}

extern "C" void kernel_launch(void* const* d_in, const int* in_sizes, int n_in,
                              void* d_out, int out_size, void* d_ws, size_t ws_size,
                              hipStream_t stream) {
  (void)in_sizes; (void)n_in; (void)d_ws; (void)ws_size; (void)out_size;
  const float* in = (const float*)d_in[0];
  float* out = (float*)d_out;
  dim3 grid(IMG / TW, IMG / TH, 16);
  MultiscaleLoG_kernel<<<grid, dim3(256), 0, stream>>>(in, out);
}

// Round 5
// 696.224 us; speedup vs baseline: 3.1134x; 2.2603x over previous
//
#include <hip/hip_runtime.h>
#include <math.h>

#define TW 64
#define TH 32
#define IMG 1024

// LDS row strides (floats). Row-stride mod 32 an odd multiple of 4 so
// consecutive rows shift bank-quads: 84%32=20, 68%32=4.
#define GSTR 84   // gray: 48 rows  (gy = y0-8 .. y0+39, gx = x0-8 .. x0+75)
#define ASTR 84   // A (vblur): 35 rows (34 used + 1 guard), ar -> gy = y0-1+ar
#define SSTR 68   // S (smooth): 34 rows, cs -> gx = x0-1+cs
#define ACCSTR 12 // per-thread accumulator: 8 floats @ stride 12 (bank step 12 -> conflict-free b128)

// ---- compile-time Gaussian weight table (doubles, then normalized to float).
// Indexed ONLY with compile-time constants -> every weight folds to an inline
// 32-bit literal in v_fmac_f32; no LDS table, no registers, no expf preamble.
constexpr double cexp_pos(double t) {   // e^t for t >= 0 via Taylor (double)
  double term = 1.0, sum = 1.0;
  for (int i = 1; i < 120; ++i) {
    term *= t / i;
    sum += term;
    if (term < 1e-300) break;
  }
  return sum;
}
constexpr double cexp(double t) { return t < 0 ? 1.0 / cexp_pos(-t) : cexp_pos(t); }

struct WTab {
  float w[189];
  constexpr WTab() : w{} {
    int off = 0;
    for (int ki = 0; ki < 7; ++ki) {          // ks = 3 + 2*ki, r = ks/2
      const int ks = 3 + 2 * ki, r = ks >> 1;
      for (int si = 0; si < 3; ++si) {        // sigma = 1 + si
        const double s = (double)(1 + si);
        double tmp[15] = {};
        double sum = 0.0;
        for (int i = 0; i < ks; ++i) {
          const double x = (double)(i - r);
          tmp[i] = cexp(-x * x / (2.0 * s * s));
          sum += tmp[i];
        }
        for (int i = 0; i < ks; ++i) w[off + i] = (float)(tmp[i] / sum);
        off += ks;
      }
    }
  }
};
constexpr WTab WT{};

// Per-scale processing. R = radius (ksize = 2R+1), OFF = offset into WT.w.
template<int R, int OFF>
__device__ __forceinline__ void do_scale(
    const float* __restrict__ gray, float* __restrict__ A, float* __restrict__ S,
    float* __restrict__ ACC, int tid, int x0, int y0)
{
  // ---- P1: vertical blur gray -> A. 20 quads x 9 row-segments (8x G=4 + 1x G=2).
  if (tid < 180) {
    const int q   = tid % 20;
    const int seg = tid / 20;
    const int ys  = seg * 4;                 // first A-row of this segment
    const bool full = (seg < 8);             // seg 8 computes only rows 32,33
    float4 a4[4];
#pragma unroll
    for (int gi = 0; gi < 4; ++gi) a4[gi] = make_float4(0.f, 0.f, 0.f, 0.f);
#pragma unroll
    for (int kk = 0; kk < 4 + 2*R; ++kk) {
      const bool kok = (kk < 2 + 2*R);
      if (full || kok) {
        const float4 v = *(const float4*)&gray[(ys + 7 - R + kk)*GSTR + 4*q];
#pragma unroll
        for (int gi = 0; gi < 4; ++gi) {
          const int d = kk - gi;             // tap index 0..2R (compile-time)
          if (d >= 0 && d <= 2*R) {
            if (gi < 2 || full) {
              const float wt = WT.w[OFF + d];   // inline literal
              a4[gi].x += wt * v.x;
              a4[gi].y += wt * v.y;
              a4[gi].z += wt * v.z;
              a4[gi].w += wt * v.w;
            }
          }
        }
      }
    }
#pragma unroll
    for (int gi = 0; gi < 4; ++gi)
      if (gi < 2 || full)
        *(float4*)&A[(ys + gi)*ASTR + 4*q] = a4[gi];
  }
  __syncthreads();

  // ---- P2: horizontal blur A -> S (34 rows x 66 cols), force 0 outside image.
  // ar = u%34: consecutive lanes step ROWS (bank step 20) -> conflict-free.
  {
    constexpr int Q0   = (7 - R) >> 2;                 // first quad rel. to col 8*cg
    constexpr int NQ   = ((14 + R) >> 2) - Q0 + 1;     // quads to load (3..6)
    constexpr int BASE = 7 - R - 4*Q0;                 // av index base
#pragma unroll 1
    for (int u = tid; u < 306; u += 256) {             // 34 rows * 9 col-groups
      const int ar = u % 34, cg = u / 34;
      float av[4*NQ];
#pragma unroll
      for (int i = 0; i < NQ; ++i)
        *(float4*)&av[4*i] = *(const float4*)&A[ar*ASTR + 8*cg + 4*(Q0 + i)];
      const int gy  = y0 - 1 + ar;
      const int gx0 = x0 - 1 + 8*cg;
      const bool rowok = ((unsigned)gy < (unsigned)IMG);
      float o8[8];
#pragma unroll
      for (int o = 0; o < 8; ++o) {
        float s = 0.f;
#pragma unroll
        for (int t = 0; t <= 2*R; ++t)
          s += WT.w[OFF + t] * av[o + BASE + t];       // inline literals
        const int gx = gx0 + o;
        // Laplacian input is smooth zero-padded by 1: outside-image slots are 0.
        o8[o] = (rowok && ((unsigned)gx < (unsigned)IMG)) ? s : 0.f;
      }
      if (cg < 8) {
        *(float4*)&S[ar*SSTR + 8*cg]     = make_float4(o8[0], o8[1], o8[2], o8[3]);
        *(float4*)&S[ar*SSTR + 8*cg + 4] = make_float4(o8[4], o8[5], o8[6], o8[7]);
      } else {                                          // last group: cols 64,65
        S[ar*SSTR + 64] = o8[0];
        S[ar*SSTR + 65] = o8[1];
      }
    }
  }
  __syncthreads();

  // ---- P3: 5-point Laplacian of S; accumulate |log| into LDS-resident ACC.
  // ACC lives in LDS (not VGPRs) so the register allocator can never spill it
  // to scratch across the 21 inlined scales (R3: ~1 GB of scratch traffic).
  // row = tid&31: consecutive lanes step rows (bank step 4) -> conflict-free.
  {
    const int row = tid & 31, cg = tid >> 5;
    float T[12], M[12], B[12];
#pragma unroll
    for (int i = 0; i < 3; ++i) {
      *(float4*)&T[4*i] = *(const float4*)&S[(row    )*SSTR + 8*cg + 4*i];
      *(float4*)&M[4*i] = *(const float4*)&S[(row + 1)*SSTR + 8*cg + 4*i];
      *(float4*)&B[4*i] = *(const float4*)&S[(row + 2)*SSTR + 8*cg + 4*i];
    }
    float4 aA = *(const float4*)&ACC[tid*ACCSTR];
    float4 aB = *(const float4*)&ACC[tid*ACCSTR + 4];
    float lg;
#define LAP(j) (T[j] + B[j] + M[(j)-1] + M[(j)+1] - 4.f*M[j])
    lg = LAP(1); aA.x += fabsf(lg);
    lg = LAP(2); aA.y += fabsf(lg);
    lg = LAP(3); aA.z += fabsf(lg);
    lg = LAP(4); aA.w += fabsf(lg);
    lg = LAP(5); aB.x += fabsf(lg);
    lg = LAP(6); aB.y += fabsf(lg);
    lg = LAP(7); aB.z += fabsf(lg);
    lg = LAP(8); aB.w += fabsf(lg);
#undef LAP
    *(float4*)&ACC[tid*ACCSTR]     = aA;
    *(float4*)&ACC[tid*ACCSTR + 4] = aB;
  }
  // NO barrier here: next P1 writes A (disjoint from S); the post-P1 barrier
  // orders this P3's S-reads against the next P2's S-writes. ACC slots are
  // per-thread private within the scale loop.
}

__global__ __launch_bounds__(256, 3)
void MultiscaleLoG_kernel(const float* __restrict__ in, float* __restrict__ out)
{
  __shared__ __align__(16) float gray[48*GSTR];
  __shared__ __align__(16) float A[35*ASTR];
  __shared__ __align__(16) float S[34*SSTR];
  __shared__ __align__(16) float ACC[256*ACCSTR];

  const int tid = threadIdx.x;
  const int x0 = blockIdx.x * TW;
  const int y0 = blockIdx.y * TH;
  const int b  = blockIdx.z;
  const float* __restrict__ base = in + (size_t)b * 3u * 1048576u;

  // zero this thread's accumulator slots (private, no barrier needed)
  *(float4*)&ACC[tid*ACCSTR]     = make_float4(0.f, 0.f, 0.f, 0.f);
  *(float4*)&ACC[tid*ACCSTR + 4] = make_float4(0.f, 0.f, 0.f, 0.f);

  // ---- gray = channel mean, staged with halo; zero outside image
  const bool interior = (x0 >= 8) & (x0 + 76 <= IMG) & (y0 >= 8) & (y0 + 40 <= IMG);
#pragma unroll 1
  for (int u = tid; u < 960; u += 256) {          // 20 quads x 48 rows
    const int q = u % 20, gr = u / 20;
    const int gx = x0 - 8 + 4*q, gy = y0 - 8 + gr;
    float4 v;
    if (interior) {
      const float* p = base + (size_t)gy * IMG + gx;
      const float4 c0 = *(const float4*)p;
      const float4 c1 = *(const float4*)(p + 1048576);
      const float4 c2 = *(const float4*)(p + 2097152);
      v.x = (c0.x + c1.x + c2.x) * (1.f/3.f);
      v.y = (c0.y + c1.y + c2.y) * (1.f/3.f);
      v.z = (c0.z + c1.z + c2.z) * (1.f/3.f);
      v.w = (c0.w + c1.w + c2.w) * (1.f/3.f);
    } else {
      float t4[4];
#pragma unroll
      for (int j = 0; j < 4; ++j) {
        const int xx = gx + j;
        float s = 0.f;
        if ((unsigned)xx < (unsigned)IMG && (unsigned)gy < (unsigned)IMG) {
          const float* p = base + (size_t)gy * IMG + xx;
          s = (p[0] + p[1048576] + p[2097152]) * (1.f/3.f);
        }
        t4[j] = s;
      }
      v = make_float4(t4[0], t4[1], t4[2], t4[3]);
    }
    *(float4*)&gray[gr*GSTR + 4*q] = v;
  }
  __syncthreads();

#define DO_KS(R, KOFF) \
  do_scale<R, (KOFF)>(gray, A, S, ACC, tid, x0, y0); \
  do_scale<R, (KOFF) + (2*(R)+1)>(gray, A, S, ACC, tid, x0, y0); \
  do_scale<R, (KOFF) + 2*(2*(R)+1)>(gray, A, S, ACC, tid, x0, y0);

  DO_KS(1, 0)
  DO_KS(2, 9)
  DO_KS(3, 24)
  DO_KS(4, 45)
  DO_KS(5, 72)
  DO_KS(6, 105)
  DO_KS(7, 144)
#undef DO_KS

  // ---- coalesced output straight from ACC (one-time permuted LDS read).
  // BARRIER REQUIRED: the read below crosses threads/waves (owner != tid);
  // all waves must have finished their last P3 ACC-write first (R4 bug).
  __syncthreads();
  {
    const int cg = tid & 7, row = tid >> 3;     // output ownership
    const int owner = (cg << 5) | row;          // thread that accumulated it
    const float4 lo = *(const float4*)&ACC[owner*ACCSTR];
    const float4 hi = *(const float4*)&ACC[owner*ACCSTR + 4];
    float* op = out + ((size_t)b * IMG + (y0 + row)) * IMG + x0 + 8*cg;
    *(float4*)&op[0] = lo;
    *(float4*)&op[4] = hi;
  }
}

extern "C" void kernel_launch(void* const* d_in, const int* in_sizes, int n_in,
                              void* d_out, int out_size, void* d_ws, size_t ws_size,
                              hipStream_t stream) {
  (void)in_sizes; (void)n_in; (void)d_ws; (void)ws_size; (void)out_size;
  const float* in = (const float*)d_in[0];
  float* out = (float*)d_out;
  dim3 grid(IMG / TW, IMG / TH, 16);
  MultiscaleLoG_kernel<<<grid, dim3(256), 0, stream>>>(in, out);
}